// Round 6
// baseline (92.711 us; speedup 1.0000x reference)
//
#include <hip/hip_runtime.h>
#include <math.h>

constexpr int N_ELEM = 8192;
constexpr int BLK    = 256;                     // pair kernel block
constexpr int WAVES_PER_BLK = 4;
constexpr int ROWS_PER_WAVE = 2;
constexpr int ROWS_PER_BLK  = WAVES_PER_BLK * ROWS_PER_WAVE;  // 8
constexpr int KP_GRID = N_ELEM / ROWS_PER_BLK;  // 1024
constexpr int BLKF    = 1024;                   // finalize kernel block
constexpr float LAMBDA = 0.1f;

// ws layout: [0, 48KB) double gpart[1024][6] {P,Ra1,Ra2,Rb1,Rb2,Rab}
// All slots written every call; no memset, no atomics.

// KP: each wave owns 2 complete rows of the masked distance matrices;
// lanes stripe over j reading raw inputs (L2-resident, wm recomputed inline).
__global__ void __launch_bounds__(BLK) kp_pairs(
        const float* __restrict__ inf, const int* __restrict__ lab,
        const float* __restrict__ tgt, const float* __restrict__ wt,
        double* __restrict__ gpart) {
    __shared__ double sred[WAVES_PER_BLK][6];
    int tx = threadIdx.x, lane = tx & 63, wid = tx >> 6;
    int r0 = blockIdx.x * ROWS_PER_BLK + wid * ROWS_PER_WAVE;

    float x0 = inf[r0],     y0 = tgt[r0];
    float x1 = inf[r0 + 1], y1 = tgt[r0 + 1];
    float u0 = (lab[r0]     == 0) ? wt[r0]     : 0.0f;
    float u1 = (lab[r0 + 1] == 0) ? wt[r0 + 1] : 0.0f;

    float ra0 = 0.f, rb0 = 0.f, pp0 = 0.f;
    float ra1 = 0.f, rb1 = 0.f, pp1 = 0.f;
#pragma unroll 4
    for (int jj = 0; jj < N_ELEM / 64; ++jj) {
        int j = jj * 64 + lane;
        float xj = inf[j], yj = tgt[j], wj = wt[j];
        int   lj = lab[j];
        float u = (lj == 0) ? wj : 0.0f;
        float d0 = x0 - xj, e0 = y0 - yj;
        ra0 = fmaf(u, fabsf(d0), ra0);
        rb0 = fmaf(u, fabsf(e0), rb0);
        pp0 = fmaf(u, fabsf(d0) * fabsf(e0), pp0);
        float d1 = x1 - xj, e1 = y1 - yj;
        ra1 = fmaf(u, fabsf(d1), ra1);
        rb1 = fmaf(u, fabsf(e1), rb1);
        pp1 = fmaf(u, fabsf(d1) * fabsf(e1), pp1);
    }
#pragma unroll
    for (int d = 32; d > 0; d >>= 1) {
        ra0 += __shfl_xor(ra0, d); rb0 += __shfl_xor(rb0, d); pp0 += __shfl_xor(pp0, d);
        ra1 += __shfl_xor(ra1, d); rb1 += __shfl_xor(rb1, d); pp1 += __shfl_xor(pp1, d);
    }
    if (lane == 0) {
        double U0 = (double)u0, U1 = (double)u1;
        double A0 = (double)ra0, B0 = (double)rb0, P0 = (double)pp0;
        double A1 = (double)ra1, B1 = (double)rb1, P1 = (double)pp1;
        sred[wid][0] = U0 * P0 + U1 * P1;
        sred[wid][1] = U0 * A0 + U1 * A1;
        sred[wid][2] = U0 * A0 * A0 + U1 * A1 * A1;
        sred[wid][3] = U0 * B0 + U1 * B1;
        sred[wid][4] = U0 * B0 * B0 + U1 * B1 * B1;
        sred[wid][5] = U0 * A0 * B0 + U1 * A1 * B1;
    }
    __syncthreads();
    if (tx == 0) {
        double* g = gpart + (size_t)blockIdx.x * 6;
#pragma unroll
        for (int k = 0; k < 6; ++k)
            g[k] = sred[0][k] + sred[1][k] + sred[2][k] + sred[3][k];
    }
}

// KF: one 1024-thread block. BCE + masked moments over raw inputs,
// gpart reduction, f64 assembly, output write.
__global__ void __launch_bounds__(BLKF) kf_final(
        const float* __restrict__ inf, const int* __restrict__ lab,
        const float* __restrict__ tgt, const float* __restrict__ wt,
        const double* __restrict__ gpart, float* __restrict__ out) {
    __shared__ float  redM[BLKF / 64][8];
    __shared__ double redG[BLKF / 64][6];
    int tx = threadIdx.x, lane = tx & 63, wid = tx >> 6;

    // phase 1: element-wise BCE + moments (8 elems/thread)
    float vb = 0.f, vn = 0.f, vw = 0.f, v1a = 0.f, v2a = 0.f, v1b = 0.f, v2b = 0.f;
#pragma unroll
    for (int k = 0; k < N_ELEM / BLKF; ++k) {
        int i = k * BLKF + tx;
        float p = inf[i];
        int   y = lab[i];
        float w = wt[i];
        float t = tgt[i];
        float logp   = fmaxf(logf(p),    -100.0f);
        float log1mp = fmaxf(log1pf(-p), -100.0f);
        float yf = (float)y;
        vb += w * -(yf * logp + (1.0f - yf) * log1mp);
        bool  m  = (y == 0);
        float mf = m ? 1.0f : 0.0f;
        float wm = m ? w : 0.0f;
        vn += mf; vw += wm;
        v1a += wm * p; v2a += wm * p * p;
        v1b += wm * t; v2b += wm * t * t;
    }
    float vm[7] = {vb, vn, vw, v1a, v2a, v1b, v2b};
#pragma unroll
    for (int k = 0; k < 7; ++k) {
        float s = vm[k];
#pragma unroll
        for (int d = 32; d > 0; d >>= 1) s += __shfl_xor(s, d);
        if (lane == 0) redM[wid][k] = s;
    }

    // phase 2: gpart[1024][6] reduction, one row per thread
    double a0, a1, a2, a3, a4, a5;
    {
        const double* g = gpart + (size_t)tx * 6;
        a0 = g[0]; a1 = g[1]; a2 = g[2]; a3 = g[3]; a4 = g[4]; a5 = g[5];
    }
#pragma unroll
    for (int d = 32; d > 0; d >>= 1) {
        a0 += __shfl_xor(a0, d); a1 += __shfl_xor(a1, d); a2 += __shfl_xor(a2, d);
        a3 += __shfl_xor(a3, d); a4 += __shfl_xor(a4, d); a5 += __shfl_xor(a5, d);
    }
    if (lane == 0) {
        redG[wid][0] = a0; redG[wid][1] = a1; redG[wid][2] = a2;
        redG[wid][3] = a3; redG[wid][4] = a4; redG[wid][5] = a5;
    }
    __syncthreads();

    if (tx == 0) {
        double M[7] = {0, 0, 0, 0, 0, 0, 0};
        double G[6] = {0, 0, 0, 0, 0, 0};
        for (int wv = 0; wv < BLKF / 64; ++wv) {
#pragma unroll
            for (int k = 0; k < 7; ++k) M[k] += (double)redM[wv][k];
#pragma unroll
            for (int k = 0; k < 6; ++k) G[k] += redG[wv][k];
        }
        double bceS = M[0], NF = M[1], W = M[2];
        double S1a = M[3], S2a = M[4], S1b = M[5], S2b = M[6];
        double P = G[0], Ra1 = G[1], Ra2 = G[2], Rb1 = G[3], Rb2 = G[4], Rab = G[5];

        double in1 = 1.0 / NF;
        double in2 = in1 * in1, in3 = in2 * in1, in4 = in2 * in2;

        double AAa = 2.0 * (W * S2a - S1a * S1a)
                   - 4.0 * Ra2 * in1 + 2.0 * W * Ra2 * in2
                   + 4.0 * Ra1 * Ra1 * in2 - 4.0 * W * Ra1 * Ra1 * in3
                   + W * W * Ra1 * Ra1 * in4;
        double BBa = 2.0 * (W * S2b - S1b * S1b)
                   - 4.0 * Rb2 * in1 + 2.0 * W * Rb2 * in2
                   + 4.0 * Rb1 * Rb1 * in2 - 4.0 * W * Rb1 * Rb1 * in3
                   + W * W * Rb1 * Rb1 * in4;
        double ABa = P
                   - 4.0 * Rab * in1 + 2.0 * W * Rab * in2
                   + 4.0 * Ra1 * Rb1 * in2 - 4.0 * W * Ra1 * Rb1 * in3
                   + W * W * Ra1 * Rb1 * in4;

        double AB = ABa * in2, AA = AAa * in2, BB = BBa * in2;
        double dcorr = (AB * AB) / (AA * BB);
        double ld = (double)LAMBDA * dcorr;
        double bce = bceS / (double)N_ELEM;
        out[0] = (float)(bce + ld);
        out[1] = (float)bce;
        out[2] = (float)ld;
    }
}

extern "C" void kernel_launch(void* const* d_in, const int* in_sizes, int n_in,
                              void* d_out, int out_size, void* d_ws, size_t ws_size,
                              hipStream_t stream) {
    const float* inf = (const float*)d_in[0];
    const int*   lab = (const int*)d_in[1];
    const float* tgt = (const float*)d_in[2];
    const float* wt  = (const float*)d_in[3];
    float* out = (float*)d_out;
    double* gpart = (double*)d_ws;

    kp_pairs<<<KP_GRID, BLK, 0, stream>>>(inf, lab, tgt, wt, gpart);
    kf_final<<<1, BLKF, 0, stream>>>(inf, lab, tgt, wt, gpart, out);
}

// Round 7
// 87.973 us; speedup vs baseline: 1.0539x; 1.0539x over previous
//
#include <hip/hip_runtime.h>
#include <math.h>

constexpr int N_ELEM = 8192;
constexpr int BLK    = 256;
constexpr int WAVES  = 4;
constexpr int RPW    = 4;                    // rows per wave
constexpr int RPB    = WAVES * RPW;          // 16 rows per block
constexpr int KP_GRID = N_ELEM / RPB;        // 512 blocks
constexpr int CHUNK  = 512;                  // j per LDS chunk
constexpr int NCHUNK = N_ELEM / CHUNK;       // 16
constexpr int BLKF   = 1024;
constexpr float LAMBDA = 0.1f;

// ws layout: [0, 24KB) double gpart[512][6] {P,Ra1,Ra2,Rb1,Rb2,Rab}
// All slots written every call; no memset, no atomics.

// KP: each wave owns 4 complete rows; j swept via double-buffered LDS chunks.
// L2 traffic: 128 KB per BLOCK (vs per wave before) = 67 MB total.
__global__ void __launch_bounds__(BLK) kp_pairs(
        const float* __restrict__ inf, const int* __restrict__ lab,
        const float* __restrict__ tgt, const float* __restrict__ wt,
        double* __restrict__ gpart) {
    __shared__ float4 sc[2][CHUNK];          // 16 KB double buffer
    __shared__ double sred[WAVES][6];
    const int tx = threadIdx.x, lane = tx & 63, wid = tx >> 6;
    const int r0 = blockIdx.x * RPB + wid * RPW;

    float x[RPW], y[RPW], u[RPW];
#pragma unroll
    for (int r = 0; r < RPW; ++r) {
        x[r] = inf[r0 + r];
        y[r] = tgt[r0 + r];
        u[r] = (lab[r0 + r] == 0) ? wt[r0 + r] : 0.0f;
    }
    float ra[RPW] = {}, rb[RPW] = {}, pp[RPW] = {};

    // prologue: stage chunk 0 (each thread stages 2 elements)
#pragma unroll
    for (int s = 0; s < CHUNK / BLK; ++s) {
        int j = s * BLK + tx;
        float wmj = (lab[j] == 0) ? wt[j] : 0.0f;
        sc[0][j] = make_float4(inf[j], tgt[j], wmj, 0.0f);
    }
    __syncthreads();

    for (int ch = 0; ch < NCHUNK; ++ch) {
        const int cur = ch & 1;
        // T14 async-stage: issue next chunk's loads BEFORE compute
        // (index wraps on last iter so loads are unconditional -> issued early)
        const int chn = (ch + 1) & (NCHUNK - 1);
        const int jb  = chn * CHUNK + tx;
        float p0n = inf[jb],       t0n = tgt[jb],       w0n = wt[jb];
        float p1n = inf[jb + BLK], t1n = tgt[jb + BLK], w1n = wt[jb + BLK];
        int   l0n = lab[jb],       l1n = lab[jb + BLK];

        // compute current chunk from LDS
#pragma unroll
        for (int s = 0; s < CHUNK / 64; ++s) {
            float4 cj = sc[cur][s * 64 + lane];
#pragma unroll
            for (int r = 0; r < RPW; ++r) {
                float fa = fabsf(x[r] - cj.x);
                float fb = fabsf(y[r] - cj.y);
                ra[r] = fmaf(cj.z, fa, ra[r]);
                rb[r] = fmaf(cj.z, fb, rb[r]);
                pp[r] = fmaf(cj.z, fa * fb, pp[r]);
            }
        }
        // write-late: next chunk into the other buffer
        if (ch + 1 < NCHUNK) {
            sc[cur ^ 1][tx]       = make_float4(p0n, t0n, (l0n == 0) ? w0n : 0.0f, 0.0f);
            sc[cur ^ 1][BLK + tx] = make_float4(p1n, t1n, (l1n == 0) ? w1n : 0.0f, 0.0f);
        }
        __syncthreads();
    }

    // finalize 4 rows per wave: butterfly-reduce 12 accumulators
#pragma unroll
    for (int r = 0; r < RPW; ++r) {
#pragma unroll
        for (int d = 32; d > 0; d >>= 1) {
            ra[r] += __shfl_xor(ra[r], d);
            rb[r] += __shfl_xor(rb[r], d);
            pp[r] += __shfl_xor(pp[r], d);
        }
    }
    if (lane == 0) {
        double s0 = 0, s1 = 0, s2 = 0, s3 = 0, s4 = 0, s5 = 0;
#pragma unroll
        for (int r = 0; r < RPW; ++r) {
            double U = (double)u[r];
            double A = (double)ra[r], B = (double)rb[r], Pp = (double)pp[r];
            s0 += U * Pp;
            s1 += U * A;  s2 += U * A * A;
            s3 += U * B;  s4 += U * B * B;
            s5 += U * A * B;
        }
        sred[wid][0] = s0; sred[wid][1] = s1; sred[wid][2] = s2;
        sred[wid][3] = s3; sred[wid][4] = s4; sred[wid][5] = s5;
    }
    __syncthreads();
    if (tx == 0) {
        double* g = gpart + (size_t)blockIdx.x * 6;
#pragma unroll
        for (int k = 0; k < 6; ++k)
            g[k] = sred[0][k] + sred[1][k] + sred[2][k] + sred[3][k];
    }
}

// KF: one 1024-thread block. BCE + masked moments over raw inputs,
// gpart reduction, f64 assembly, output write.
__global__ void __launch_bounds__(BLKF) kf_final(
        const float* __restrict__ inf, const int* __restrict__ lab,
        const float* __restrict__ tgt, const float* __restrict__ wt,
        const double* __restrict__ gpart, float* __restrict__ out) {
    __shared__ float  redM[BLKF / 64][8];
    __shared__ double redG[BLKF / 64][6];
    int tx = threadIdx.x, lane = tx & 63, wid = tx >> 6;

    // phase 1: element-wise BCE + moments (8 elems/thread)
    float vb = 0.f, vn = 0.f, vw = 0.f, v1a = 0.f, v2a = 0.f, v1b = 0.f, v2b = 0.f;
#pragma unroll
    for (int k = 0; k < N_ELEM / BLKF; ++k) {
        int i = k * BLKF + tx;
        float p = inf[i];
        int   y = lab[i];
        float w = wt[i];
        float t = tgt[i];
        float logp   = fmaxf(logf(p),    -100.0f);
        float log1mp = fmaxf(log1pf(-p), -100.0f);
        float yf = (float)y;
        vb += w * -(yf * logp + (1.0f - yf) * log1mp);
        bool  m  = (y == 0);
        float mf = m ? 1.0f : 0.0f;
        float wm = m ? w : 0.0f;
        vn += mf; vw += wm;
        v1a += wm * p; v2a += wm * p * p;
        v1b += wm * t; v2b += wm * t * t;
    }
    float vm[7] = {vb, vn, vw, v1a, v2a, v1b, v2b};
#pragma unroll
    for (int k = 0; k < 7; ++k) {
        float s = vm[k];
#pragma unroll
        for (int d = 32; d > 0; d >>= 1) s += __shfl_xor(s, d);
        if (lane == 0) redM[wid][k] = s;
    }

    // phase 2: gpart[512][6] reduction, one row per thread (tx<512)
    double a0 = 0, a1 = 0, a2 = 0, a3 = 0, a4 = 0, a5 = 0;
    if (tx < KP_GRID) {
        const double* g = gpart + (size_t)tx * 6;
        a0 = g[0]; a1 = g[1]; a2 = g[2]; a3 = g[3]; a4 = g[4]; a5 = g[5];
    }
#pragma unroll
    for (int d = 32; d > 0; d >>= 1) {
        a0 += __shfl_xor(a0, d); a1 += __shfl_xor(a1, d); a2 += __shfl_xor(a2, d);
        a3 += __shfl_xor(a3, d); a4 += __shfl_xor(a4, d); a5 += __shfl_xor(a5, d);
    }
    if (lane == 0) {
        redG[wid][0] = a0; redG[wid][1] = a1; redG[wid][2] = a2;
        redG[wid][3] = a3; redG[wid][4] = a4; redG[wid][5] = a5;
    }
    __syncthreads();

    if (tx == 0) {
        double M[7] = {0, 0, 0, 0, 0, 0, 0};
        double G[6] = {0, 0, 0, 0, 0, 0};
        for (int wv = 0; wv < BLKF / 64; ++wv) {
#pragma unroll
            for (int k = 0; k < 7; ++k) M[k] += (double)redM[wv][k];
#pragma unroll
            for (int k = 0; k < 6; ++k) G[k] += redG[wv][k];
        }
        double bceS = M[0], NF = M[1], W = M[2];
        double S1a = M[3], S2a = M[4], S1b = M[5], S2b = M[6];
        double P = G[0], Ra1 = G[1], Ra2 = G[2], Rb1 = G[3], Rb2 = G[4], Rab = G[5];

        double in1 = 1.0 / NF;
        double in2 = in1 * in1, in3 = in2 * in1, in4 = in2 * in2;

        double AAa = 2.0 * (W * S2a - S1a * S1a)
                   - 4.0 * Ra2 * in1 + 2.0 * W * Ra2 * in2
                   + 4.0 * Ra1 * Ra1 * in2 - 4.0 * W * Ra1 * Ra1 * in3
                   + W * W * Ra1 * Ra1 * in4;
        double BBa = 2.0 * (W * S2b - S1b * S1b)
                   - 4.0 * Rb2 * in1 + 2.0 * W * Rb2 * in2
                   + 4.0 * Rb1 * Rb1 * in2 - 4.0 * W * Rb1 * Rb1 * in3
                   + W * W * Rb1 * Rb1 * in4;
        double ABa = P
                   - 4.0 * Rab * in1 + 2.0 * W * Rab * in2
                   + 4.0 * Ra1 * Rb1 * in2 - 4.0 * W * Ra1 * Rb1 * in3
                   + W * W * Ra1 * Rb1 * in4;

        double AB = ABa * in2, AA = AAa * in2, BB = BBa * in2;
        double dcorr = (AB * AB) / (AA * BB);
        double ld = (double)LAMBDA * dcorr;
        double bce = bceS / (double)N_ELEM;
        out[0] = (float)(bce + ld);
        out[1] = (float)bce;
        out[2] = (float)ld;
    }
}

extern "C" void kernel_launch(void* const* d_in, const int* in_sizes, int n_in,
                              void* d_out, int out_size, void* d_ws, size_t ws_size,
                              hipStream_t stream) {
    const float* inf = (const float*)d_in[0];
    const int*   lab = (const int*)d_in[1];
    const float* tgt = (const float*)d_in[2];
    const float* wt  = (const float*)d_in[3];
    float* out = (float*)d_out;
    double* gpart = (double*)d_ws;

    kp_pairs<<<KP_GRID, BLK, 0, stream>>>(inf, lab, tgt, wt, gpart);
    kf_final<<<1, BLKF, 0, stream>>>(inf, lab, tgt, wt, gpart, out);
}

// Round 8
// 85.245 us; speedup vs baseline: 1.0876x; 1.0320x over previous
//
#include <hip/hip_runtime.h>
#include <math.h>

constexpr int N_ELEM = 8192;
constexpr int BLK    = 256;
constexpr int WAVES  = 4;
constexpr int RPW    = 4;                    // rows per wave
constexpr int RPB    = WAVES * RPW;          // 16 rows per block
constexpr int KP_GRID = N_ELEM / RPB;        // 512 blocks (max; ~272 active)
constexpr int CHUNK  = 512;                  // j per LDS chunk
constexpr int BLKF   = 1024;
constexpr float LAMBDA = 0.1f;

// ws layout (no memset, no atomics; every used slot written every call):
//   [0, 24576)      double gpart[512][6] {P,Ra1,Ra2,Rb1,Rb2,Rab}
//   [24576, 24580)  int cnt   (written by k1 block 0)
constexpr size_t OFF_CNT = 24576;

// K1: deterministic atomic-free compaction of the label==0 subset.
// Each block redundantly counts zeros before its range (L2-hot 32KB scan)
// -> global write offset. Subset packs to front of c[], complement to the
// back with w=0. All 8192 slots written; order irrelevant (symmetric sums).
__global__ void __launch_bounds__(BLK) k1_compact(
        const float* __restrict__ inf, const int* __restrict__ lab,
        const float* __restrict__ tgt, const float* __restrict__ wt,
        float4* __restrict__ c, int* __restrict__ pcnt) {
    __shared__ int swc[WAVES];       // per-wave zero counts (this block)
    __shared__ int r2[WAVES][2];     // per-wave partial {zerosBeforeBlock, zerosTotal}
    const int tx = threadIdx.x, lane = tx & 63, wid = tx >> 6;
    const int blockStart = blockIdx.x * BLK;
    const int i = blockStart + tx;

    float p = inf[i], t = tgt[i], w = wt[i];
    bool  m = (lab[i] == 0);

    // global zero counts: before this block, and total
    int czb = 0, czt = 0;
    for (int k = tx; k < N_ELEM; k += BLK) {
        int z = (lab[k] == 0) ? 1 : 0;
        czt += z;
        czb += (k < blockStart) ? z : 0;
    }
#pragma unroll
    for (int d = 32; d > 0; d >>= 1) {
        czb += __shfl_xor(czb, d);
        czt += __shfl_xor(czt, d);
    }

    // intra-block prefix
    unsigned long long bal = __ballot(m);
    int pz  = __popcll(bal & ((1ull << lane) - 1ull));  // zeros before lane in wave
    int wzc = __popcll(bal);                             // zeros in this wave

    if (lane == 0) { swc[wid] = wzc; r2[wid][0] = czb; r2[wid][1] = czt; }
    __syncthreads();

    int zb = 0;                                          // zeros in block before my wave
#pragma unroll
    for (int v = 0; v < WAVES; ++v) zb += (v < wid) ? swc[v] : 0;
    int gzb = r2[0][0] + r2[1][0] + r2[2][0] + r2[3][0]; // zeros before block
    int gzt = r2[0][1] + r2[1][1] + r2[2][1] + r2[3][1]; // total zeros

    int pos;
    if (m) {
        pos = gzb + zb + pz;                             // front-compacted
    } else {
        int nzb_global = blockStart - gzb;               // nonzeros before block
        int nzb_wave   = wid * 64 - zb;                  // nonzeros in block before wave
        int nz_lane    = lane - pz;                      // nonzeros before lane in wave
        pos = N_ELEM - 1 - (nzb_global + nzb_wave + nz_lane);
    }
    c[pos] = make_float4(p, t, m ? w : 0.0f, 0.0f);

    if (blockIdx.x == 0 && tx == 0) *pcnt = gzt;
}

// KP: pair sums over the compacted subset only. Each wave owns 4 rows;
// j swept via double-buffered LDS chunks with early-issued prefetch (T14).
__global__ void __launch_bounds__(BLK) kp_pairs(
        const float4* __restrict__ c, const int* __restrict__ pcnt,
        double* __restrict__ gpart) {
    __shared__ float4 sc[2][CHUNK];          // 16 KB double buffer
    __shared__ double sred[WAVES][6];
    const int tx = threadIdx.x, lane = tx & 63, wid = tx >> 6;
    const int cnt = *pcnt;
    const int nActive = (cnt + RPB - 1) / RPB;
    double* g = gpart + (size_t)blockIdx.x * 6;

    if ((int)blockIdx.x >= nActive) {        // uniform exit; keep gpart defined
        if (tx == 0) { g[0] = 0; g[1] = 0; g[2] = 0; g[3] = 0; g[4] = 0; g[5] = 0; }
        return;
    }
    const int nch = (cnt + CHUNK - 1) / CHUNK;   // chunks to sweep (<=16)
    const int r0  = blockIdx.x * RPB + wid * RPW;

    float x[RPW], y[RPW], u[RPW];
#pragma unroll
    for (int r = 0; r < RPW; ++r) {
        float4 cr = c[r0 + r];
        x[r] = cr.x; y[r] = cr.y; u[r] = cr.z;   // u=0 for pad rows
    }
    float ra[RPW] = {}, rb[RPW] = {}, pp[RPW] = {};

    // prologue: stage chunk 0
    sc[0][tx]       = c[tx];
    sc[0][BLK + tx] = c[BLK + tx];
    __syncthreads();

    for (int ch = 0; ch < nch; ++ch) {
        const int cur = ch & 1;
        // prefetch next chunk early (clamped index -> unconditional issue)
        const int chn = (ch + 1 < nch) ? ch + 1 : nch - 1;
        const int jb  = chn * CHUNK + tx;
        float4 n0 = c[jb];
        float4 n1 = c[jb + BLK];

        // compute current chunk from LDS (pad entries have w=0)
#pragma unroll
        for (int s = 0; s < CHUNK / 64; ++s) {
            float4 cj = sc[cur][s * 64 + lane];
#pragma unroll
            for (int r = 0; r < RPW; ++r) {
                float fa = fabsf(x[r] - cj.x);
                float fb = fabsf(y[r] - cj.y);
                ra[r] = fmaf(cj.z, fa, ra[r]);
                rb[r] = fmaf(cj.z, fb, rb[r]);
                pp[r] = fmaf(cj.z, fa * fb, pp[r]);
            }
        }
        if (ch + 1 < nch) {
            sc[cur ^ 1][tx]       = n0;
            sc[cur ^ 1][BLK + tx] = n1;
        }
        __syncthreads();
    }

#pragma unroll
    for (int r = 0; r < RPW; ++r) {
#pragma unroll
        for (int d = 32; d > 0; d >>= 1) {
            ra[r] += __shfl_xor(ra[r], d);
            rb[r] += __shfl_xor(rb[r], d);
            pp[r] += __shfl_xor(pp[r], d);
        }
    }
    if (lane == 0) {
        double s0 = 0, s1 = 0, s2 = 0, s3 = 0, s4 = 0, s5 = 0;
#pragma unroll
        for (int r = 0; r < RPW; ++r) {
            double U = (double)u[r];
            double A = (double)ra[r], B = (double)rb[r], Pp = (double)pp[r];
            s0 += U * Pp;
            s1 += U * A;  s2 += U * A * A;
            s3 += U * B;  s4 += U * B * B;
            s5 += U * A * B;
        }
        sred[wid][0] = s0; sred[wid][1] = s1; sred[wid][2] = s2;
        sred[wid][3] = s3; sred[wid][4] = s4; sred[wid][5] = s5;
    }
    __syncthreads();
    if (tx == 0) {
#pragma unroll
        for (int k = 0; k < 6; ++k)
            g[k] = sred[0][k] + sred[1][k] + sred[2][k] + sred[3][k];
    }
}

// KF: one 1024-thread block. BCE + masked moments over raw inputs,
// gpart reduction, f64 assembly, output write. (Unchanged from R7.)
__global__ void __launch_bounds__(BLKF) kf_final(
        const float* __restrict__ inf, const int* __restrict__ lab,
        const float* __restrict__ tgt, const float* __restrict__ wt,
        const double* __restrict__ gpart, float* __restrict__ out) {
    __shared__ float  redM[BLKF / 64][8];
    __shared__ double redG[BLKF / 64][6];
    int tx = threadIdx.x, lane = tx & 63, wid = tx >> 6;

    float vb = 0.f, vn = 0.f, vw = 0.f, v1a = 0.f, v2a = 0.f, v1b = 0.f, v2b = 0.f;
#pragma unroll
    for (int k = 0; k < N_ELEM / BLKF; ++k) {
        int i = k * BLKF + tx;
        float p = inf[i];
        int   y = lab[i];
        float w = wt[i];
        float t = tgt[i];
        float logp   = fmaxf(logf(p),    -100.0f);
        float log1mp = fmaxf(log1pf(-p), -100.0f);
        float yf = (float)y;
        vb += w * -(yf * logp + (1.0f - yf) * log1mp);
        bool  m  = (y == 0);
        float mf = m ? 1.0f : 0.0f;
        float wm = m ? w : 0.0f;
        vn += mf; vw += wm;
        v1a += wm * p; v2a += wm * p * p;
        v1b += wm * t; v2b += wm * t * t;
    }
    float vm[7] = {vb, vn, vw, v1a, v2a, v1b, v2b};
#pragma unroll
    for (int k = 0; k < 7; ++k) {
        float s = vm[k];
#pragma unroll
        for (int d = 32; d > 0; d >>= 1) s += __shfl_xor(s, d);
        if (lane == 0) redM[wid][k] = s;
    }

    double a0 = 0, a1 = 0, a2 = 0, a3 = 0, a4 = 0, a5 = 0;
    if (tx < KP_GRID) {
        const double* gr = gpart + (size_t)tx * 6;
        a0 = gr[0]; a1 = gr[1]; a2 = gr[2]; a3 = gr[3]; a4 = gr[4]; a5 = gr[5];
    }
#pragma unroll
    for (int d = 32; d > 0; d >>= 1) {
        a0 += __shfl_xor(a0, d); a1 += __shfl_xor(a1, d); a2 += __shfl_xor(a2, d);
        a3 += __shfl_xor(a3, d); a4 += __shfl_xor(a4, d); a5 += __shfl_xor(a5, d);
    }
    if (lane == 0) {
        redG[wid][0] = a0; redG[wid][1] = a1; redG[wid][2] = a2;
        redG[wid][3] = a3; redG[wid][4] = a4; redG[wid][5] = a5;
    }
    __syncthreads();

    if (tx == 0) {
        double M[7] = {0, 0, 0, 0, 0, 0, 0};
        double G[6] = {0, 0, 0, 0, 0, 0};
        for (int wv = 0; wv < BLKF / 64; ++wv) {
#pragma unroll
            for (int k = 0; k < 7; ++k) M[k] += (double)redM[wv][k];
#pragma unroll
            for (int k = 0; k < 6; ++k) G[k] += redG[wv][k];
        }
        double bceS = M[0], NF = M[1], W = M[2];
        double S1a = M[3], S2a = M[4], S1b = M[5], S2b = M[6];
        double P = G[0], Ra1 = G[1], Ra2 = G[2], Rb1 = G[3], Rb2 = G[4], Rab = G[5];

        double in1 = 1.0 / NF;
        double in2 = in1 * in1, in3 = in2 * in1, in4 = in2 * in2;

        double AAa = 2.0 * (W * S2a - S1a * S1a)
                   - 4.0 * Ra2 * in1 + 2.0 * W * Ra2 * in2
                   + 4.0 * Ra1 * Ra1 * in2 - 4.0 * W * Ra1 * Ra1 * in3
                   + W * W * Ra1 * Ra1 * in4;
        double BBa = 2.0 * (W * S2b - S1b * S1b)
                   - 4.0 * Rb2 * in1 + 2.0 * W * Rb2 * in2
                   + 4.0 * Rb1 * Rb1 * in2 - 4.0 * W * Rb1 * Rb1 * in3
                   + W * W * Rb1 * Rb1 * in4;
        double ABa = P
                   - 4.0 * Rab * in1 + 2.0 * W * Rab * in2
                   + 4.0 * Ra1 * Rb1 * in2 - 4.0 * W * Ra1 * Rb1 * in3
                   + W * W * Ra1 * Rb1 * in4;

        double AB = ABa * in2, AA = AAa * in2, BB = BBa * in2;
        double dcorr = (AB * AB) / (AA * BB);
        double ld = (double)LAMBDA * dcorr;
        double bce = bceS / (double)N_ELEM;
        out[0] = (float)(bce + ld);
        out[1] = (float)bce;
        out[2] = (float)ld;
    }
}

extern "C" void kernel_launch(void* const* d_in, const int* in_sizes, int n_in,
                              void* d_out, int out_size, void* d_ws, size_t ws_size,
                              hipStream_t stream) {
    const float* inf = (const float*)d_in[0];
    const int*   lab = (const int*)d_in[1];
    const float* tgt = (const float*)d_in[2];
    const float* wt  = (const float*)d_in[3];
    float* out = (float*)d_out;

    double* gpart = (double*)d_ws;
    int*    pcnt  = (int*)((char*)d_ws + OFF_CNT);
    float4* c     = (float4*)((char*)d_ws + OFF_CNT + 256);

    k1_compact<<<N_ELEM / BLK, BLK, 0, stream>>>(inf, lab, tgt, wt, c, pcnt);
    kp_pairs<<<KP_GRID, BLK, 0, stream>>>(c, pcnt, gpart);
    kf_final<<<1, BLKF, 0, stream>>>(inf, lab, tgt, wt, gpart, out);
}